// Round 5
// baseline (704.612 us; speedup 1.0000x reference)
//
#include <hip/hip_runtime.h>
#include <cstddef>

#define H_ 256
#define W_ 256
#define HW_ 65536

typedef unsigned int uint;
typedef unsigned short ushort;
typedef __attribute__((ext_vector_type(8))) short short8;
typedef __attribute__((ext_vector_type(16))) float floatx16;

__device__ __forceinline__ float bf2f(ushort u) {
    return __uint_as_float(((uint)u) << 16);
}
__device__ __forceinline__ ushort f2bf(float f) {
    uint u = __float_as_uint(f);
    uint r = (u + 0x7fffu + ((u >> 16) & 1u)) >> 16;
    return (ushort)r;
}
__device__ __forceinline__ float sigmoidf_(float x) {
    return 1.0f / (1.0f + expf(-x));
}

// ============ weight prep: OIHW fp32 -> MFMA-fragment-ordered bf16 ============
__device__ __forceinline__ void prep_one(const float* src, ushort* dst,
                                         int CO, int CI, int e) {
    int chunk = e / 9216;
    int r = e - chunk * 9216;
    int co = r / 288;
    int kk = r - co * 288;
    int khw = kk >> 5;
    int ci = kk & 31;
    int cig = chunk * 32 + ci;
    float v = 0.f;
    if (co < CO && cig < CI) v = src[(co * CI + cig) * 9 + khw];
    int s = kk >> 4;
    int lane = ((kk >> 3) & 1) * 32 + co;
    int j = kk & 7;
    dst[(((size_t)chunk * 18 + s) * 64 + lane) * 8 + j] = f2bf(v);
}

__global__ __launch_bounds__(256) void prep_weights(
    const float* __restrict__ w_in, const float* __restrict__ w2,
    const float* __restrict__ w3, const float* __restrict__ aw1,
    const float* __restrict__ aw2,
    ushort* __restrict__ w_inB, ushort* __restrict__ w2B,
    ushort* __restrict__ w3B, ushort* __restrict__ aw1B,
    ushort* __restrict__ aw2B, ushort* __restrict__ zp) {
    int idx = blockIdx.x * 256 + threadIdx.x;
    if (idx < 64) zp[idx] = 0;
    if (idx < 9216)        prep_one(w_in, w_inB, 32, 32, idx);
    else if (idx < 46080)  prep_one(w2, w2B, 32, 128, idx - 9216);
    else if (idx < 82944)  prep_one(w3, w3B, 32, 128, idx - 46080);
    else if (idx < 92160)  prep_one(aw1, aw1B, 16, 32, idx - 82944);
    else if (idx < 101376) prep_one(aw2, aw2B, 16, 16, idx - 92160);
}

// ============ x: NCHW fp32 -> NHWC bf16 (32 ch) ============
__global__ __launch_bounds__(256) void transform_x(const float* __restrict__ x,
                                                   ushort* __restrict__ xh) {
    __shared__ float s[64][33];
    const int t = threadIdx.x;
    const int w0 = blockIdx.x * 64, h = blockIdx.y, b = blockIdx.z;
    {
        int ww = t & 63, c0 = (t >> 6) * 8;
#pragma unroll
        for (int j = 0; j < 8; j++) {
            int c = c0 + j;
            s[ww][c] = x[((size_t)(b * 32 + c)) * HW_ + h * W_ + w0 + ww];
        }
    }
    __syncthreads();
    {
        int p = t >> 2, cb = t & 3;
        ushort tmp[8];
#pragma unroll
        for (int j = 0; j < 8; j++) tmp[j] = f2bf(s[p][cb * 8 + j]);
        *(uint4*)(xh + (((size_t)b * HW_ + h * W_ + w0 + p) * 32) + cb * 8) =
            *(const uint4*)tmp;
    }
}

// ============ implicit-GEMM conv 3x3 pad=1, NHWC bf16, MFMA 32x32x16 ============
// Single-buffer LDS (21.76 KB -> high block residency), global_load_lds staging,
// deduped A-reads: 4 rows x 3 kw x 2 k-halves = 24 ds_read_b128 feeding 36 MFMAs.
template<int NCHUNK, int COOUT, bool RELU>
__global__ __launch_bounds__(256, 4) void conv_mfma(
    const ushort* __restrict__ in0, const ushort* __restrict__ in1,
    const ushort* __restrict__ in2, const ushort* __restrict__ in3,
    const ushort* __restrict__ wB, const ushort* __restrict__ zp,
    ushort* __restrict__ outp) {
    __shared__ __align__(16) ushort smem[1360 * 8];  // 10 rows x [4 cb][34 px] x 16B
    const int t = threadIdx.x;
    const int wid = t >> 6;
    const int lane = t & 63;
    const int lco = lane & 31, lhalf = lane >> 5;
    const int w0 = blockIdx.x * 32, h0 = blockIdx.y * 8, b = blockIdx.z;
    const ushort* ins[4] = {in0, in1, in2, in3};

    floatx16 acc0, acc1;
#pragma unroll
    for (int i = 0; i < 16; i++) { acc0[i] = 0.f; acc1[i] = 0.f; }

    for (int ch = 0; ch < NCHUNK; ch++) {
        __syncthreads();  // smem free: all waves done reading previous chunk
        {
            const ushort* inp = ins[ch];
#pragma unroll
            for (int i = 0; i < 6; i++) {
                int u = i * 256 + t;
                if (u < 1360) {
                    int row = u / 136;
                    int rem = u - row * 136;
                    int cb = rem / 34;
                    int p = rem - cb * 34;
                    int gh = h0 - 1 + row, gw = w0 - 1 + p;
                    const ushort* src = ((unsigned)gh < 256u && (unsigned)gw < 256u)
                        ? (inp + (((size_t)b * HW_ + (size_t)gh * W_ + gw) * 32 + cb * 8))
                        : zp;
                    __builtin_amdgcn_global_load_lds(
                        (const __attribute__((address_space(1))) unsigned int*)src,
                        (__attribute__((address_space(3))) unsigned int*)(smem + (size_t)(i * 256 + (t & ~63)) * 8),
                        16, 0, 0);
                }
            }
        }
        __syncthreads();  // staged data visible (vmcnt drained by barrier semantics)

        const ushort* wbp = wB + ((size_t)ch * 18 * 64 + lane) * 8;
#pragma unroll
        for (int half = 0; half < 2; half++) {
            short8 bf[9];
#pragma unroll
            for (int j = 0; j < 9; j++)
                bf[j] = *(const short8*)(wbp + (size_t)(2 * j + half) * 512);
            const int cbr = half * 2 + lhalf;
#pragma unroll
            for (int kw = 0; kw < 3; kw++) {
                const int ww = lco + kw;
                short8 a[4];
#pragma unroll
                for (int r = 0; r < 4; r++)
                    a[r] = *(const short8*)(smem + (size_t)((wid * 2 + r) * 136 + cbr * 34 + ww) * 8);
#pragma unroll
                for (int kh = 0; kh < 3; kh++) {
                    acc0 = __builtin_amdgcn_mfma_f32_32x32x16_bf16(a[kh], bf[kh * 3 + kw], acc0, 0, 0, 0);
                    acc1 = __builtin_amdgcn_mfma_f32_32x32x16_bf16(a[kh + 1], bf[kh * 3 + kw], acc1, 0, 0, 0);
                }
            }
        }
    }

    // epilogue: D col = co = lane&31; pixel row = (r&3) + 8*(r>>2) + 4*half
#pragma unroll
    for (int r = 0; r < 16; r++) {
        int prow = (r & 3) + 8 * (r >> 2) + 4 * lhalf;
        float v0 = acc0[r], v1 = acc1[r];
        if (RELU) { v0 = fmaxf(v0, 0.f); v1 = fmaxf(v1, 0.f); }
        ushort u0 = (lco < COOUT) ? f2bf(v0) : (ushort)0;
        ushort u1 = (lco < COOUT) ? f2bf(v1) : (ushort)0;
        size_t p0 = (((size_t)b * HW_ + (h0 + wid * 2) * W_ + w0 + prow) * 32) + lco;
        outp[p0] = u0;
        outp[p0 + (size_t)W_ * 32] = u1;
    }
}

// ============ attention head: 1x1 conv (16->4) + bias + sigmoid ============
__global__ __launch_bounds__(256) void att1x1(const ushort* __restrict__ a2,
                                              const float* __restrict__ w,
                                              const float* __restrict__ bias,
                                              ushort* __restrict__ wmap) {
    int idx = blockIdx.x * 256 + threadIdx.x;  // 8*HW
    float xin[16];
    {
        uint4 v0 = *(const uint4*)(a2 + (size_t)idx * 32);
        uint4 v1 = *(const uint4*)(a2 + (size_t)idx * 32 + 8);
        const ushort* u = (const ushort*)&v0;
#pragma unroll
        for (int j = 0; j < 8; j++) xin[j] = bf2f(u[j]);
        const ushort* u2 = (const ushort*)&v1;
#pragma unroll
        for (int j = 0; j < 8; j++) xin[8 + j] = bf2f(u2[j]);
    }
    ushort o[4];
#pragma unroll
    for (int g = 0; g < 4; g++) {
        float acc = bias[g];
#pragma unroll
        for (int ci = 0; ci < 16; ci++) acc = fmaf(xin[ci], w[g * 16 + ci], acc);
        o[g] = f2bf(sigmoidf_(acc));
    }
    *(uint2*)(wmap + (size_t)idx * 4) = *(const uint2*)o;
}

// ============ final 1x1 conv (32->1) + sigmoid, fp32 out ============
__global__ __launch_bounds__(256) void out1x1(const ushort* __restrict__ feat,
                                              const float* __restrict__ w,
                                              float* __restrict__ out) {
    int idx = blockIdx.x * 256 + threadIdx.x;
    float acc = 0.f;
    const ushort* f = feat + (size_t)idx * 32;
#pragma unroll
    for (int q = 0; q < 4; q++) {
        uint4 v = *(const uint4*)(f + q * 8);
        const ushort* u = (const ushort*)&v;
#pragma unroll
        for (int j = 0; j < 8; j++) acc = fmaf(bf2f(u[j]), w[q * 8 + j], acc);
    }
    out[idx] = sigmoidf_(acc);
}

// ============ segmented IRNN scan + gating, both directions in one dispatch ====
// relu(x + a*prev) has |d cur/d prev| <= a (=0.2): a 24-step warmup from zero
// converges the segment state to ~2e-17 relative -> invisible at bf16.
// Thread = (channel c, chain-seg). chain-seg = (b, dir, seg, col).
// VERT: scan h (col = w). HORZ: scan w (col = h).
template<int VERT>
__global__ __launch_bounds__(256) void scan_seg(
    const ushort* __restrict__ feat, const float* __restrict__ alpha,
    const ushort* __restrict__ wmap, ushort* __restrict__ gfwd,
    ushort* __restrict__ gbwd, int gf, int gb) {
    const int t = threadIdx.x;
    const int c = t & 31;
    const int idx = blockIdx.x * 8 + (t >> 5);
    const int col = idx & 255;
    const int seg = (idx >> 8) & 3;
    const int dir = (idx >> 10) & 1;  // wave-uniform (8 | 1024)
    const int b = idx >> 11;
    const float a = alpha[c];

    size_t pixBase, step;
    if (VERT) { pixBase = (size_t)b * HW_ + col;              step = 256; }
    else      { pixBase = (size_t)b * HW_ + (size_t)col * W_; step = 1; }
    const size_t fstep = step * 32, wstep = step * 4;
    const ushort* fp = feat + pixBase * 32 + c;
    const ushort* wp = wmap + pixBase * 4 + (dir ? gb : gf);
    ushort* gp = (dir ? gbwd : gfwd) + pixBase * 32 + c;

    const int main0 = seg * 64;
    const int start = (seg == 0) ? 0 : main0 - 24;
    const int nb = (main0 - start) / 8 + 8;  // 8 or 11 batches of 8

    ushort xr[2][8], wr[2][8];
    auto loadb = [&](int bi, int buf) {
#pragma unroll
        for (int j = 0; j < 8; j++) {
            int p = start + bi * 8 + j;
            int phys = dir ? 255 - p : p;
            xr[buf][j] = fp[(size_t)phys * fstep];
            wr[buf][j] = wp[(size_t)phys * wstep];
        }
    };
    loadb(0, 0);
    loadb(1, 1);
    float prev = 0.f;
    for (int i = 0; i < nb; i++) {
        int bp = start + i * 8;
        int buf = i & 1;
        if (bp >= main0) {
#pragma unroll
            for (int j = 0; j < 8; j++) {
                int p = bp + j;
                int phys = dir ? 255 - p : p;
                float cur = fmaxf(fmaf(a, prev, bf2f(xr[buf][j])), 0.f);
                prev = cur;
                gp[(size_t)phys * fstep] = f2bf(cur * bf2f(wr[buf][j]));
            }
        } else {
#pragma unroll
            for (int j = 0; j < 8; j++) {
                float cur = fmaxf(fmaf(a, prev, bf2f(xr[buf][j])), 0.f);
                prev = cur;
            }
        }
        if (i + 2 < nb) loadb(i + 2, buf);
    }
}

extern "C" void kernel_launch(void* const* d_in, const int* in_sizes, int n_in,
                              void* d_out, int out_size, void* d_ws, size_t ws_size,
                              hipStream_t stream) {
    const float* x      = (const float*)d_in[0];
    const float* alpha1 = (const float*)d_in[1];
    const float* alpha2 = (const float*)d_in[2];
    const float* w_in   = (const float*)d_in[3];
    const float* w2     = (const float*)d_in[4];
    const float* w3     = (const float*)d_in[5];
    const float* aw1    = (const float*)d_in[6];
    const float* aw2    = (const float*)d_in[7];
    const float* aw3    = (const float*)d_in[8];
    const float* ab3    = (const float*)d_in[9];
    const float* wout   = (const float*)d_in[10];
    float* out = (float*)d_out;

    // ---- workspace carve (ushorts), ~206 MB ----
    const size_t TEN = (size_t)8 * HW_ * 32;
    ushort* p = (ushort*)d_ws;
    ushort* xh    = p; p += TEN;
    ushort* feat  = p; p += TEN;
    ushort* g0    = p; p += TEN;
    ushort* g1    = p; p += TEN;
    ushort* g2    = p; p += TEN;
    ushort* g3    = p; p += TEN;
    ushort* wmap  = p; p += (size_t)8 * HW_ * 4;
    ushort* w_inB = p; p += 9216;
    ushort* w2B   = p; p += 36864;
    ushort* w3B   = p; p += 36864;
    ushort* aw1B  = p; p += 9216;
    ushort* aw2B  = p; p += 9216;
    ushort* zp    = p; p += 64;

    prep_weights<<<396, 256, 0, stream>>>(w_in, w2, w3, aw1, aw2,
                                          w_inB, w2B, w3B, aw1B, aw2B, zp);
    transform_x<<<dim3(4, 256, 8), 256, 0, stream>>>(x, xh);

    dim3 gconv(8, 32, 8);
    // attention gate (a1/a2 overlay g0/g1)
    conv_mfma<1, 16, true><<<gconv, 256, 0, stream>>>(xh, xh, xh, xh, aw1B, zp, g0);
    conv_mfma<1, 16, true><<<gconv, 256, 0, stream>>>(g0, g0, g0, g0, aw2B, zp, g1);
    att1x1<<<2048, 256, 0, stream>>>(g1, aw3, ab3, wmap);

    // trunk
    conv_mfma<1, 32, false><<<gconv, 256, 0, stream>>>(xh, xh, xh, xh, w_inB, zp, feat);

    // round 1 scans: g0=td, g1=lr, g2=dt, g3=rl
    scan_seg<1><<<2048, 256, 0, stream>>>(feat, alpha1, wmap, g0, g2, 0, 2);
    scan_seg<0><<<2048, 256, 0, stream>>>(feat, alpha1, wmap, g1, g3, 1, 3);

    conv_mfma<4, 32, false><<<gconv, 256, 0, stream>>>(g0, g1, g2, g3, w2B, zp, feat);

    // round 2 scans
    scan_seg<1><<<2048, 256, 0, stream>>>(feat, alpha2, wmap, g0, g2, 0, 2);
    scan_seg<0><<<2048, 256, 0, stream>>>(feat, alpha2, wmap, g1, g3, 1, 3);

    conv_mfma<4, 32, true><<<gconv, 256, 0, stream>>>(g0, g1, g2, g3, w3B, zp, feat);

    out1x1<<<2048, 256, 0, stream>>>(feat, wout, out);
}

// Round 6
// 399.143 us; speedup vs baseline: 1.7653x; 1.7653x over previous
//
#include <hip/hip_runtime.h>
#include <cstddef>

#define H_ 256
#define W_ 256
#define HW_ 65536

typedef unsigned int uint;
typedef unsigned short ushort;
typedef __attribute__((ext_vector_type(8))) short short8;
typedef __attribute__((ext_vector_type(16))) float floatx16;

__device__ __forceinline__ float bf2f(ushort u) {
    return __uint_as_float(((uint)u) << 16);
}
__device__ __forceinline__ ushort f2bf(float f) {
    uint u = __float_as_uint(f);
    uint r = (u + 0x7fffu + ((u >> 16) & 1u)) >> 16;
    return (ushort)r;
}
__device__ __forceinline__ float sigmoidf_(float x) {
    return 1.0f / (1.0f + expf(-x));
}

// ============ weight prep: OIHW fp32 -> MFMA-fragment-ordered bf16 ============
__device__ __forceinline__ void prep_one(const float* src, ushort* dst,
                                         int CO, int CI, int e) {
    int chunk = e / 9216;
    int r = e - chunk * 9216;
    int co = r / 288;
    int kk = r - co * 288;
    int khw = kk >> 5;
    int ci = kk & 31;
    int cig = chunk * 32 + ci;
    float v = 0.f;
    if (co < CO && cig < CI) v = src[(co * CI + cig) * 9 + khw];
    int s = kk >> 4;
    int lane = ((kk >> 3) & 1) * 32 + co;
    int j = kk & 7;
    dst[(((size_t)chunk * 18 + s) * 64 + lane) * 8 + j] = f2bf(v);
}

__global__ __launch_bounds__(256) void prep_weights(
    const float* __restrict__ w_in, const float* __restrict__ w2,
    const float* __restrict__ w3, const float* __restrict__ aw1,
    const float* __restrict__ aw2,
    ushort* __restrict__ w_inB, ushort* __restrict__ w2B,
    ushort* __restrict__ w3B, ushort* __restrict__ aw1B,
    ushort* __restrict__ aw2B, ushort* __restrict__ zp) {
    int idx = blockIdx.x * 256 + threadIdx.x;
    if (idx < 64) zp[idx] = 0;
    if (idx < 9216)        prep_one(w_in, w_inB, 32, 32, idx);
    else if (idx < 46080)  prep_one(w2, w2B, 32, 128, idx - 9216);
    else if (idx < 82944)  prep_one(w3, w3B, 32, 128, idx - 46080);
    else if (idx < 92160)  prep_one(aw1, aw1B, 16, 32, idx - 82944);
    else if (idx < 101376) prep_one(aw2, aw2B, 16, 16, idx - 92160);
}

// ============ x: NCHW fp32 -> NHWC bf16 (32 ch) ============
__global__ __launch_bounds__(256) void transform_x(const float* __restrict__ x,
                                                   ushort* __restrict__ xh) {
    __shared__ float s[64][33];
    const int t = threadIdx.x;
    const int w0 = blockIdx.x * 64, h = blockIdx.y, b = blockIdx.z;
    {
        int ww = t & 63, c0 = (t >> 6) * 8;
#pragma unroll
        for (int j = 0; j < 8; j++) {
            int c = c0 + j;
            s[ww][c] = x[((size_t)(b * 32 + c)) * HW_ + h * W_ + w0 + ww];
        }
    }
    __syncthreads();
    {
        int p = t >> 2, cb = t & 3;
        ushort tmp[8];
#pragma unroll
        for (int j = 0; j < 8; j++) tmp[j] = f2bf(s[p][cb * 8 + j]);
        *(uint4*)(xh + (((size_t)b * HW_ + h * W_ + w0 + p) * 32) + cb * 8) =
            *(const uint4*)tmp;
    }
}

// ============ implicit-GEMM conv 3x3 pad=1, NHWC bf16, MFMA 32x32x16 ============
template<int NCHUNK, int COOUT, bool RELU>
__global__ __launch_bounds__(256, 4) void conv_mfma(
    const ushort* __restrict__ in0, const ushort* __restrict__ in1,
    const ushort* __restrict__ in2, const ushort* __restrict__ in3,
    const ushort* __restrict__ wB, const ushort* __restrict__ zp,
    ushort* __restrict__ outp) {
    __shared__ __align__(16) ushort smem[1360 * 8];  // 10 rows x [4 cb][34 px] x 16B
    const int t = threadIdx.x;
    const int wid = t >> 6;
    const int lane = t & 63;
    const int lco = lane & 31, lhalf = lane >> 5;
    const int w0 = blockIdx.x * 32, h0 = blockIdx.y * 8, b = blockIdx.z;
    const ushort* ins[4] = {in0, in1, in2, in3};

    floatx16 acc0, acc1;
#pragma unroll
    for (int i = 0; i < 16; i++) { acc0[i] = 0.f; acc1[i] = 0.f; }

    for (int ch = 0; ch < NCHUNK; ch++) {
        __syncthreads();
        {
            const ushort* inp = ins[ch];
#pragma unroll
            for (int i = 0; i < 6; i++) {
                int u = i * 256 + t;
                if (u < 1360) {
                    int row = u / 136;
                    int rem = u - row * 136;
                    int cb = rem / 34;
                    int p = rem - cb * 34;
                    int gh = h0 - 1 + row, gw = w0 - 1 + p;
                    const ushort* src = ((unsigned)gh < 256u && (unsigned)gw < 256u)
                        ? (inp + (((size_t)b * HW_ + (size_t)gh * W_ + gw) * 32 + cb * 8))
                        : zp;
                    __builtin_amdgcn_global_load_lds(
                        (const __attribute__((address_space(1))) unsigned int*)src,
                        (__attribute__((address_space(3))) unsigned int*)(smem + (size_t)(i * 256 + (t & ~63)) * 8),
                        16, 0, 0);
                }
            }
        }
        __syncthreads();

        const ushort* wbp = wB + ((size_t)ch * 18 * 64 + lane) * 8;
#pragma unroll
        for (int half = 0; half < 2; half++) {
            short8 bf[9];
#pragma unroll
            for (int j = 0; j < 9; j++)
                bf[j] = *(const short8*)(wbp + (size_t)(2 * j + half) * 512);
            const int cbr = half * 2 + lhalf;
#pragma unroll
            for (int kw = 0; kw < 3; kw++) {
                const int ww = lco + kw;
                short8 a[4];
#pragma unroll
                for (int r = 0; r < 4; r++)
                    a[r] = *(const short8*)(smem + (size_t)((wid * 2 + r) * 136 + cbr * 34 + ww) * 8);
#pragma unroll
                for (int kh = 0; kh < 3; kh++) {
                    acc0 = __builtin_amdgcn_mfma_f32_32x32x16_bf16(a[kh], bf[kh * 3 + kw], acc0, 0, 0, 0);
                    acc1 = __builtin_amdgcn_mfma_f32_32x32x16_bf16(a[kh + 1], bf[kh * 3 + kw], acc1, 0, 0, 0);
                }
            }
        }
    }

#pragma unroll
    for (int r = 0; r < 16; r++) {
        int prow = (r & 3) + 8 * (r >> 2) + 4 * lhalf;
        float v0 = acc0[r], v1 = acc1[r];
        if (RELU) { v0 = fmaxf(v0, 0.f); v1 = fmaxf(v1, 0.f); }
        ushort u0 = (lco < COOUT) ? f2bf(v0) : (ushort)0;
        ushort u1 = (lco < COOUT) ? f2bf(v1) : (ushort)0;
        size_t p0 = (((size_t)b * HW_ + (h0 + wid * 2) * W_ + w0 + prow) * 32) + lco;
        outp[p0] = u0;
        outp[p0 + (size_t)W_ * 32] = u1;
    }
}

// ============ attention head: 1x1 conv (16->4) + bias + sigmoid ============
// writes 4 direction PLANES: wmapT[g][b][pix]
__global__ __launch_bounds__(256) void att1x1(const ushort* __restrict__ a2,
                                              const float* __restrict__ w,
                                              const float* __restrict__ bias,
                                              ushort* __restrict__ wmapT) {
    int idx = blockIdx.x * 256 + threadIdx.x;  // b*HW + pix over 8*HW
    float xin[16];
    {
        uint4 v0 = *(const uint4*)(a2 + (size_t)idx * 32);
        uint4 v1 = *(const uint4*)(a2 + (size_t)idx * 32 + 8);
        const ushort* u = (const ushort*)&v0;
#pragma unroll
        for (int j = 0; j < 8; j++) xin[j] = bf2f(u[j]);
        const ushort* u2 = (const ushort*)&v1;
#pragma unroll
        for (int j = 0; j < 8; j++) xin[8 + j] = bf2f(u2[j]);
    }
#pragma unroll
    for (int g = 0; g < 4; g++) {
        float acc = bias[g];
#pragma unroll
        for (int ci = 0; ci < 16; ci++) acc = fmaf(xin[ci], w[g * 16 + ci], acc);
        wmapT[(size_t)g * 8 * HW_ + idx] = f2bf(sigmoidf_(acc));
    }
}

// ============ final 1x1 conv (32->1) + sigmoid, fp32 out ============
__global__ __launch_bounds__(256) void out1x1(const ushort* __restrict__ feat,
                                              const float* __restrict__ w,
                                              float* __restrict__ out) {
    int idx = blockIdx.x * 256 + threadIdx.x;
    float acc = 0.f;
    const ushort* f = feat + (size_t)idx * 32;
#pragma unroll
    for (int q = 0; q < 4; q++) {
        uint4 v = *(const uint4*)(f + q * 8);
        const ushort* u = (const ushort*)&v;
#pragma unroll
        for (int j = 0; j < 8; j++) acc = fmaf(bf2f(u[j]), w[q * 8 + j], acc);
    }
    out[idx] = sigmoidf_(acc);
}

// ============ segmented IRNN scan, vectorized 8ch/thread, both dirs ============
// 8 segments of 32 + 16-step warmup (alpha<=0.2 -> 0.2^16 ~ 5e-12, invisible
// at bf16; R5 validated warmup semantics). Thread = (ch-group cg, col) within
// block; block = (colblk, seg, dir, b). 16B loads/stores, 4-deep ring prefetch.
template<int VERT>
__global__ __launch_bounds__(256) void scan_seg(
    const ushort* __restrict__ feat, const float* __restrict__ alpha,
    const ushort* __restrict__ wmapT, ushort* __restrict__ gfwd,
    ushort* __restrict__ gbwd, int gf, int gb) {
    const int t = threadIdx.x;
    const int cg = t & 3;
    const int bx = blockIdx.x;
    const int col = (bx & 3) * 64 + (t >> 2);
    const int seg = (bx >> 2) & 7;
    const int dir = (bx >> 5) & 1;
    const int b = bx >> 6;
    const int c0 = cg * 8;

    float a[8];
#pragma unroll
    for (int j = 0; j < 8; j++) a[j] = alpha[c0 + j];

    const ushort* wplane = wmapT + (size_t)(dir ? gb : gf) * 8 * HW_ + (size_t)b * HW_;
    ushort* gout = dir ? gbwd : gfwd;

    const int main0 = seg * 32;
    const int start = (seg == 0) ? 0 : main0 - 16;
    const int cnt = main0 - start + 32;  // 32 or 48 (multiple of 4)

    auto pixof = [&](int p) -> size_t {
        int phys = dir ? 255 - p : p;
        return VERT ? ((size_t)phys * W_ + col) : ((size_t)col * W_ + phys);
    };

    uint4 xv[4];
    ushort wv[4];
#pragma unroll
    for (int k = 0; k < 4; k++) {
        size_t pix = pixof(start + k);
        xv[k] = *(const uint4*)(feat + ((size_t)b * HW_ + pix) * 32 + c0);
        wv[k] = wplane[pix];
    }
    float prev[8];
#pragma unroll
    for (int j = 0; j < 8; j++) prev[j] = 0.f;

    for (int i = 0; i < cnt; i += 4) {
#pragma unroll
        for (int k = 0; k < 4; k++) {
            const int p = start + i + k;
            uint4 xcur = xv[k];
            ushort wcur = wv[k];
            if (i + k + 4 < cnt) {
                size_t pix = pixof(p + 4);
                xv[k] = *(const uint4*)(feat + ((size_t)b * HW_ + pix) * 32 + c0);
                wv[k] = wplane[pix];
            }
            const ushort* xu = (const ushort*)&xcur;
            if (p >= main0) {
                float wmv = bf2f(wcur);
                ushort o[8];
#pragma unroll
                for (int j = 0; j < 8; j++) {
                    float cur = fmaxf(fmaf(a[j], prev[j], bf2f(xu[j])), 0.f);
                    prev[j] = cur;
                    o[j] = f2bf(cur * wmv);
                }
                *(uint4*)(gout + ((size_t)b * HW_ + pixof(p)) * 32 + c0) = *(const uint4*)o;
            } else {
#pragma unroll
                for (int j = 0; j < 8; j++)
                    prev[j] = fmaxf(fmaf(a[j], prev[j], bf2f(xu[j])), 0.f);
            }
        }
    }
}

extern "C" void kernel_launch(void* const* d_in, const int* in_sizes, int n_in,
                              void* d_out, int out_size, void* d_ws, size_t ws_size,
                              hipStream_t stream) {
    const float* x      = (const float*)d_in[0];
    const float* alpha1 = (const float*)d_in[1];
    const float* alpha2 = (const float*)d_in[2];
    const float* w_in   = (const float*)d_in[3];
    const float* w2     = (const float*)d_in[4];
    const float* w3     = (const float*)d_in[5];
    const float* aw1    = (const float*)d_in[6];
    const float* aw2    = (const float*)d_in[7];
    const float* aw3    = (const float*)d_in[8];
    const float* ab3    = (const float*)d_in[9];
    const float* wout   = (const float*)d_in[10];
    float* out = (float*)d_out;

    // ---- workspace carve (ushorts), ~206 MB ----
    const size_t TEN = (size_t)8 * HW_ * 32;
    ushort* p = (ushort*)d_ws;
    ushort* xh    = p; p += TEN;
    ushort* feat  = p; p += TEN;
    ushort* g0    = p; p += TEN;
    ushort* g1    = p; p += TEN;
    ushort* g2    = p; p += TEN;
    ushort* g3    = p; p += TEN;
    ushort* wmapT = p; p += (size_t)4 * 8 * HW_;
    ushort* w_inB = p; p += 9216;
    ushort* w2B   = p; p += 36864;
    ushort* w3B   = p; p += 36864;
    ushort* aw1B  = p; p += 9216;
    ushort* aw2B  = p; p += 9216;
    ushort* zp    = p; p += 64;

    prep_weights<<<396, 256, 0, stream>>>(w_in, w2, w3, aw1, aw2,
                                          w_inB, w2B, w3B, aw1B, aw2B, zp);
    transform_x<<<dim3(4, 256, 8), 256, 0, stream>>>(x, xh);

    dim3 gconv(8, 32, 8);
    // attention gate (a1/a2 overlay g0/g1)
    conv_mfma<1, 16, true><<<gconv, 256, 0, stream>>>(xh, xh, xh, xh, aw1B, zp, g0);
    conv_mfma<1, 16, true><<<gconv, 256, 0, stream>>>(g0, g0, g0, g0, aw2B, zp, g1);
    att1x1<<<2048, 256, 0, stream>>>(g1, aw3, ab3, wmapT);

    // trunk
    conv_mfma<1, 32, false><<<gconv, 256, 0, stream>>>(xh, xh, xh, xh, w_inB, zp, feat);

    // round 1 scans: g0=td, g1=lr, g2=dt, g3=rl
    scan_seg<1><<<512, 256, 0, stream>>>(feat, alpha1, wmapT, g0, g2, 0, 2);
    scan_seg<0><<<512, 256, 0, stream>>>(feat, alpha1, wmapT, g1, g3, 1, 3);

    conv_mfma<4, 32, false><<<gconv, 256, 0, stream>>>(g0, g1, g2, g3, w2B, zp, feat);

    // round 2 scans
    scan_seg<1><<<512, 256, 0, stream>>>(feat, alpha2, wmapT, g0, g2, 0, 2);
    scan_seg<0><<<512, 256, 0, stream>>>(feat, alpha2, wmapT, g1, g3, 1, 3);

    conv_mfma<4, 32, true><<<gconv, 256, 0, stream>>>(g0, g1, g2, g3, w3B, zp, feat);

    out1x1<<<2048, 256, 0, stream>>>(feat, wout, out);
}